// Round 8
// baseline (136.169 us; speedup 1.0000x reference)
//
#include <hip/hip_runtime.h>
#include <hip/hip_bf16.h>

#define NCOLS 32768
#define NZ 64
#define NT 40
#define DTF 30.0f
#define GAMMAC 0.55f

typedef _Float16 f16;

// Cap the pre-RA scheduler's prefetch window (r4->r5: removed ~200MB of
// scratch-spill HBM traffic caused by hoisted ds_read live ranges).
#define SBAR() __builtin_amdgcn_sched_barrier(0)

// swap lane pairs (0,1),(2,3),... : u<->v partner exchange
__device__ __forceinline__ float dpp_swap1(float x) {
    return __int_as_float(__builtin_amdgcn_mov_dpp(__float_as_int(x), 0xB1, 0xF, 0xF, true));
}
__device__ __forceinline__ unsigned int packh2(float a, float b) {
    union { f16 h[2]; unsigned int u; } v;
    v.h[0] = (f16)a; v.h[1] = (f16)b; return v.u;
}
__device__ __forceinline__ unsigned short f16bits(float a) {
    union { f16 h; unsigned short u; } v; v.h = (f16)a; return v.u;
}
__device__ __forceinline__ float lo16f(unsigned int x) {
    union { unsigned int u; f16 h[2]; } v; v.u = x; return (float)v.h[0];
}
__device__ __forceinline__ float hi16f(unsigned int x) {
    union { unsigned int u; f16 h[2]; } v; v.u = x; return (float)v.h[1];
}

// History: allocator caps this kernel at ~88 VGPRs (r2/r3/r6: anything
// bigger spills to scratch at ~650GB/s). r5/r7: LDS-issue + VALU jointly
// bound. This version removes per-pipe WASTE via field-per-wave layout:
//   waves 0,1: u,v interleaved lane&1 (dpp quad-swap partner) for cols
//              0..31 / 32..63 -- skip FG reads (boundary forcing in 2 f32
//              regs), keep Coriolis.
//   waves 2,3: t,s interleaved -- skip swap/Coriolis (identity), read FG.
// LDS: W 32KB [k4][type][col] + CP 16KB + FG(ts only) 16KB = 64KB.
// Wave-uniform branches; same f16 coefficient math as r7 (absmax 0.25).
__global__ __launch_bounds__(256, 2) void scm_kernel(
    const float* __restrict__ u0, const float* __restrict__ v0,
    const float* __restrict__ t0, const float* __restrict__ s0,
    const float* __restrict__ hz, const float* __restrict__ akv,
    const float* __restrict__ akt, const float* __restrict__ tfo,
    const float* __restrict__ sfo, const float* __restrict__ uss,
    const float* __restrict__ vss, const float* __restrict__ usb,
    const float* __restrict__ vsb, const float* __restrict__ fcor,
    float* __restrict__ out)
{
    __shared__ uint4 Wsh[16 * 128];   // [k4][type*64+cb] 4 levels (hg,-e) = 32KB
    __shared__ uint2 CPsh[16 * 128];  // [k4][type*64+cb] 4 levels -cp     = 16KB
    __shared__ uint2 FGsh[16 * 128];  // [k4][(wv-2)*64+lane] 4 levels fg  = 16KB

    const int ltid  = threadIdx.x;
    const int wv    = ltid >> 6;          // wave 0..3
    const int lane  = ltid & 63;
    const bool isUV = (wv < 2);
    const int fld01 = lane & 1;           // 0: u/t, 1: v/s
    const int cb    = ((wv & 1) << 5) + (lane >> 1);   // column in block 0..63
    const int col   = blockIdx.x * 64 + cb;
    const int field = (isUV ? 0 : 2) + fld01;
    const int tb    = isUV ? 0 : 1;       // coefficient type: akv / akt
    const int tsoff = ((wv - 2) & 1) * 64 + lane;      // FG slot (ts waves)

    const float* ak  = isUV ? akv : akt;
    const float* st0 = (field == 0) ? u0 : (field == 1) ? v0
                     : (field == 2) ? t0 : s0;

    // Coriolis scalars + boundary stresses (u,v waves only; wave-uniform)
    float alpha = 1.0f, beta = 0.0f, bnd0 = 0.f, bnd63 = 0.f;
    if (isUV) {
        float fc   = fcor[col];
        float dtfc = DTF * fc;
        float cff  = dtfc * dtfc;
        float cff1 = 1.0f / (1.0f + GAMMAC * GAMMAC * cff);
        float coefc = 1.0f - GAMMAC * (1.0f - GAMMAC) * cff;
        alpha = cff1 * coefc;
        beta  = (fld01 == 0) ? cff1 * dtfc : -cff1 * dtfc;
        bnd0  = -DTF * ((fld01 == 0) ? usb : vsb)[col];
        bnd63 =  DTF * ((fld01 == 0) ? uss : vss)[col];
    }

    const float* hzc = hz + (size_t)col * NZ;
    const float* akc = ak + (size_t)col * (NZ + 1);
    const float* fr  = isUV ? nullptr
                            : (((fld01 == 0) ? tfo : sfo) + (size_t)col * NZ);

    // ---- build folded Thomas coefficients, streamed, packed 4 levels ----
    // a[k] = -2dt*ak[k]/(hz[k-1]+hz[k]); c[k]=a[k+1]; b[k]=hz[k]-a[k]-c[k]
    // g=1/(b-a*cp_prev); publish hg=hz*g, e=a*g, cp=c*g (f16); fg=rhs*g:
    // f16 in LDS for t,s; f32 regs gb0/gb63 for u,v (boundary-only rhs).
    float gb0 = 0.f, gb63 = 0.f;
    {
        float cpprev = 0.f, aik = 0.f, hk = hzc[0];
        uint4 wacc; uint2 cpacc, fgacc;
        #pragma unroll
        for (int k = 0; k < NZ; ++k) {
            float hk1 = 0.f, aik1 = 0.f;
            if (k < NZ - 1) {
                hk1  = hzc[k + 1];
                aik1 = (-2.0f * DTF) * akc[k + 1] / (hk + hk1);
            }
            float bk    = hk - aik - aik1;
            float denom = bk - aik * cpprev;
            float g     = 1.0f / denom;
            float cpk   = aik1 * g;
            if (isUV) {
                if (k == 0)      gb0  = bnd0  * g;
                if (k == NZ - 1) gb63 = bnd63 * g;
            } else {
                unsigned short fv = f16bits((DTF * fr[k]) * g);
                switch (k & 3) {
                    case 0: fgacc.x = fv; break;
                    case 1: fgacc.x |= ((unsigned int)fv << 16); break;
                    case 2: fgacc.y = fv; break;
                    default:
                        fgacc.y |= ((unsigned int)fv << 16);
                        FGsh[(k >> 2) * 128 + tsoff] = fgacc;
                        break;
                }
            }
            unsigned int   wvp = packh2(hk * g, -aik * g);
            unsigned short cv  = f16bits(-cpk);
            switch (k & 3) {
                case 0: wacc.x = wvp; cpacc.x = cv; break;
                case 1: wacc.y = wvp; cpacc.x |= ((unsigned int)cv << 16); break;
                case 2: wacc.z = wvp; cpacc.y = cv; break;
                default:
                    wacc.w = wvp; cpacc.y |= ((unsigned int)cv << 16);
                    if ((lane & 1) == 0) {
                        Wsh[(k >> 2) * 128 + tb * 64 + cb]  = wacc;
                        CPsh[(k >> 2) * 128 + tb * 64 + cb] = cpacc;
                    }
                    break;
            }
            cpprev = cpk; aik = aik1; hk = hk1;
            if ((k & 15) == 15) SBAR();
        }
    }

    // ---- load state ----
    float tau[NZ];
    {
        const float4* sp = (const float4*)(st0 + (size_t)col * NZ);
        #pragma unroll
        for (int k4 = 0; k4 < NZ / 4; ++k4) {
            float4 s = sp[k4];
            tau[4*k4+0] = s.x; tau[4*k4+1] = s.y;
            tau[4*k4+2] = s.z; tau[4*k4+3] = s.w;
        }
    }

    // deviation shift for t,s (solve conserves constants exactly): evolve
    // tau = state - mean, re-add at the end -> f16 coefficient rounding
    // cannot excite the conserved mode.
    float meanadd = 0.0f;
    if (!isUV) {
        float ssum = 0.f;
        #pragma unroll
        for (int k = 0; k < NZ; ++k) ssum += tau[k];
        meanadd = ssum * (1.0f / NZ);
        #pragma unroll
        for (int k = 0; k < NZ; ++k) tau[k] -= meanadd;
    }

    __syncthreads();   // coefficients published; LDS read-only from here on

    // ---- 40 time steps: tau in regs, coefficients via wide LDS reads ----
    for (int n = 0; n < NT; ++n) {
        float dpprev = 0.f;
        if (isUV) {
            #pragma unroll
            for (int k4 = 0; k4 < 16; ++k4) {
                uint4 w = Wsh[k4 * 128 + cb];             // type 0
                #pragma unroll
                for (int j = 0; j < 4; ++j) {
                    unsigned int wvp = (j == 0) ? w.x : (j == 1) ? w.y
                                     : (j == 2) ? w.z : w.w;
                    const int k = 4*k4 + j;
                    float own = tau[k];
                    float oth = dpp_swap1(own);               // partner u<->v
                    float m   = fmaf(beta, oth, alpha * own);
                    float dp;
                    if (k == 0) {
                        dp = fmaf(lo16f(wvp), m, gb0);        // e[0]=0
                    } else if (k == NZ - 1) {
                        dp = fmaf(lo16f(wvp), m, gb63);
                        dp = fmaf(hi16f(wvp), dpprev, dp);
                    } else {
                        dp = fmaf(hi16f(wvp), dpprev, lo16f(wvp) * m);
                    }
                    tau[k] = dp;
                    dpprev = dp;
                }
                if ((k4 & 3) == 3) SBAR();
            }
        } else {
            #pragma unroll
            for (int k4 = 0; k4 < 16; ++k4) {
                uint4 w   = Wsh[k4 * 128 + 64 + cb];      // type 1
                uint2 fg4 = FGsh[k4 * 128 + tsoff];
                #pragma unroll
                for (int j = 0; j < 4; ++j) {
                    unsigned int wvp = (j == 0) ? w.x : (j == 1) ? w.y
                                     : (j == 2) ? w.z : w.w;
                    float fgv = (j == 0) ? lo16f(fg4.x) : (j == 1) ? hi16f(fg4.x)
                              : (j == 2) ? lo16f(fg4.y) : hi16f(fg4.y);
                    const int k = 4*k4 + j;
                    float dp = fmaf(lo16f(wvp), tau[k], fgv); // hg*tau + fg
                    dp = fmaf(hi16f(wvp), dpprev, dp);        // - e*dp_prev
                    tau[k] = dp;
                    dpprev = dp;
                }
                if ((k4 & 3) == 3) SBAR();
            }
        }
        float xn = 0.f;
        #pragma unroll
        for (int k4 = 15; k4 >= 0; --k4) {
            uint2 cp4 = CPsh[k4 * 128 + tb * 64 + cb];
            float x3 = fmaf(hi16f(cp4.y), xn, tau[4*k4+3]); tau[4*k4+3] = x3;
            float x2 = fmaf(lo16f(cp4.y), x3, tau[4*k4+2]); tau[4*k4+2] = x2;
            float x1 = fmaf(hi16f(cp4.x), x2, tau[4*k4+1]); tau[4*k4+1] = x1;
            float x0 = fmaf(lo16f(cp4.x), x1, tau[4*k4+0]); tau[4*k4+0] = x0;
            xn = x0;
            if ((k4 & 3) == 0) SBAR();
        }
    }

    // ---- store f32 output: out[field][col][k] ----
    float* op = out + ((size_t)field * NCOLS + col) * NZ;
    #pragma unroll
    for (int k4 = 0; k4 < NZ / 4; ++k4) {
        float4 w;
        w.x = tau[4*k4+0] + meanadd;
        w.y = tau[4*k4+1] + meanadd;
        w.z = tau[4*k4+2] + meanadd;
        w.w = tau[4*k4+3] + meanadd;
        ((float4*)op)[k4] = w;
    }
}

extern "C" void kernel_launch(void* const* d_in, const int* in_sizes, int n_in,
                              void* d_out, int out_size, void* d_ws, size_t ws_size,
                              hipStream_t stream) {
    const float* u0   = (const float*)d_in[0];
    const float* v0   = (const float*)d_in[1];
    const float* t0   = (const float*)d_in[2];
    const float* s0   = (const float*)d_in[3];
    const float* hz   = (const float*)d_in[4];
    const float* akv  = (const float*)d_in[5];
    const float* akt  = (const float*)d_in[6];
    const float* tfo  = (const float*)d_in[7];
    const float* sfo  = (const float*)d_in[8];
    const float* uss  = (const float*)d_in[9];
    const float* vss  = (const float*)d_in[10];
    const float* usb  = (const float*)d_in[11];
    const float* vsb  = (const float*)d_in[12];
    const float* fcor = (const float*)d_in[13];

    scm_kernel<<<dim3(NCOLS / 64), dim3(256), 0, stream>>>(
        u0, v0, t0, s0, hz, akv, akt, tfo, sfo, uss, vss, usb, vsb, fcor,
        (float*)d_out);
}